// Round 9
// baseline (14245.456 us; speedup 1.0000x reference)
//
#include <hip/hip_runtime.h>
#include <math.h>

#define NP 16384
#define SP 4096
#define CINCH 32
#define CO 64
#define KK 16
#define GRIDC 16
#define NCELLS 4096
#define NW 128        // worker blocks in k_mega

// ---------------- helpers ----------------
__device__ __forceinline__ float waveGemm64(float xv, const float* __restrict__ wl, int c) {
  float a0=0.f,a1=0.f,a2=0.f,a3=0.f;
  #pragma unroll
  for (int k=0;k<64;k+=4){
    a0 = fmaf(__shfl(xv,k  ), wl[(k  )*CO+c], a0);
    a1 = fmaf(__shfl(xv,k+1), wl[(k+1)*CO+c], a1);
    a2 = fmaf(__shfl(xv,k+2), wl[(k+2)*CO+c], a2);
    a3 = fmaf(__shfl(xv,k+3), wl[(k+3)*CO+c], a3);
  }
  return (a0+a1)+(a2+a3);
}

__device__ __forceinline__ int morton12(int x,int y,int z){
  int m=0;
  #pragma unroll
  for (int b=0;b<4;b++){
    m |= ((x>>b)&1)<<(3*b) | ((y>>b)&1)<<(3*b+1) | ((z>>b)&1)<<(3*b+2);
  }
  return m;
}

template<int NS>
__device__ __forceinline__ void mergeQ(const float* __restrict__ pv, const int* __restrict__ pi,
                                       int* __restrict__ outp){
  int pos[NS]; float hv[NS]; int hi[NS];
  #pragma unroll
  for (int p=0;p<NS;p++){ pos[p]=0; hv[p]=pv[p*KK]; hi[p]=pi[p*KK]; }
  #pragma unroll
  for (int k=0;k<KK;k++){
    int best=0; float bv=hv[0]; int bi=hi[0];
    #pragma unroll
    for (int p=1;p<NS;p++){
      bool g=(hv[p]<bv)||((hv[p]==bv)&&(hi[p]<bi));
      if (g){ bv=hv[p]; bi=hi[p]; best=p; }
    }
    outp[k]=bi;
    #pragma unroll
    for (int p=0;p<NS;p++) if (best==p){
      pos[p]++;
      bool ok = pos[p]<KK;
      hv[p] = ok ? pv[p*KK+pos[p]] : 3.4e38f;
      hi[p] = ok ? pi[p*KK+pos[p]] : 0x7fffffff;
    }
  }
}

// worker-blocks barrier: arrive + spin on device-scope counter (zeroed per launch)
__device__ __forceinline__ void wbar(int* ctr, int target){
  __syncthreads();
  if (threadIdx.x==0){
    __threadfence();
    atomicAdd(ctr,1);
    while (atomicAdd(ctr,0) < target) __builtin_amdgcn_s_sleep(2);
    __threadfence();
  }
  __syncthreads();
}

// ---------------- small prep kernels ----------------
__global__ __launch_bounds__(256) void k_pts4(const float* __restrict__ pts, float4* __restrict__ pts4) {
  int i = blockIdx.x*256 + threadIdx.x;
  float x = pts[3*i], y = pts[3*i+1], z = pts[3*i+2];
  pts4[i] = make_float4(x,y,z, x*x + y*y + z*z);
}

__global__ __launch_bounds__(1024) void k_bbox(const float4* __restrict__ pts4, float* __restrict__ bbox) {
  __shared__ float red[6][16];
  int t = threadIdx.x;
  float mnx=3e38f,mny=3e38f,mnz=3e38f,mxx=-3e38f,mxy=-3e38f,mxz=-3e38f;
  for (int i=t;i<NP;i+=1024){
    float4 p = pts4[i];
    mnx=fminf(mnx,p.x); mny=fminf(mny,p.y); mnz=fminf(mnz,p.z);
    mxx=fmaxf(mxx,p.x); mxy=fmaxf(mxy,p.y); mxz=fmaxf(mxz,p.z);
  }
  #pragma unroll
  for (int o=1;o<64;o<<=1){
    mnx=fminf(mnx,__shfl_xor(mnx,o)); mny=fminf(mny,__shfl_xor(mny,o)); mnz=fminf(mnz,__shfl_xor(mnz,o));
    mxx=fmaxf(mxx,__shfl_xor(mxx,o)); mxy=fmaxf(mxy,__shfl_xor(mxy,o)); mxz=fmaxf(mxz,__shfl_xor(mxz,o));
  }
  if ((t&63)==0){
    int w=t>>6;
    red[0][w]=mnx; red[1][w]=mny; red[2][w]=mnz; red[3][w]=mxx; red[4][w]=mxy; red[5][w]=mxz;
  }
  __syncthreads();
  if (t==0){
    float a0=red[0][0],a1=red[1][0],a2=red[2][0],a3=red[3][0],a4=red[4][0],a5=red[5][0];
    for (int w=1;w<16;w++){
      a0=fminf(a0,red[0][w]); a1=fminf(a1,red[1][w]); a2=fminf(a2,red[2][w]);
      a3=fmaxf(a3,red[3][w]); a4=fmaxf(a4,red[4][w]); a5=fmaxf(a5,red[5][w]);
    }
    bbox[0]=a0; bbox[1]=a1; bbox[2]=a2; bbox[3]=a3; bbox[4]=a4; bbox[5]=a5;
  }
}

__global__ __launch_bounds__(256) void k_cellhist(const float4* __restrict__ pts4,
    const float* __restrict__ bbox, int* __restrict__ hist) {
  int i = blockIdx.x*256 + threadIdx.x;
  float4 p = pts4[i];
  float sx=(float)GRIDC/(bbox[3]-bbox[0]+1e-6f);
  float sy=(float)GRIDC/(bbox[4]-bbox[1]+1e-6f);
  float sz=(float)GRIDC/(bbox[5]-bbox[2]+1e-6f);
  int cx=min(GRIDC-1,max(0,(int)((p.x-bbox[0])*sx)));
  int cy=min(GRIDC-1,max(0,(int)((p.y-bbox[1])*sy)));
  int cz=min(GRIDC-1,max(0,(int)((p.z-bbox[2])*sz)));
  atomicAdd(&hist[morton12(cx,cy,cz)],1);
}

__global__ __launch_bounds__(1024) void k_scan(const int* __restrict__ hist, int* __restrict__ cellStart) {
  __shared__ int wsum[16];
  int t = threadIdx.x;
  int h0=hist[4*t], h1=hist[4*t+1], h2=hist[4*t+2], h3=hist[4*t+3];
  int T = h0+h1+h2+h3;
  int incl = T;
  #pragma unroll
  for (int o=1;o<64;o<<=1){
    int n = __shfl_up(incl,o);
    if ((t&63)>=o) incl += n;
  }
  if ((t&63)==63) wsum[t>>6]=incl;
  __syncthreads();
  int woff=0;
  for (int i=0;i<(t>>6);i++) woff += wsum[i];
  int excl = woff + incl - T;
  cellStart[4*t]=excl; cellStart[4*t+1]=excl+h0; cellStart[4*t+2]=excl+h0+h1; cellStart[4*t+3]=excl+h0+h1+h2;
}

__global__ __launch_bounds__(256) void k_scatter(const float4* __restrict__ pts4,
    const float* __restrict__ bbox, const int* __restrict__ cellStart, int* __restrict__ cursor,
    float4* __restrict__ pfp) {
  int i = blockIdx.x*256 + threadIdx.x;
  float4 p = pts4[i];
  float sx=(float)GRIDC/(bbox[3]-bbox[0]+1e-6f);
  float sy=(float)GRIDC/(bbox[4]-bbox[1]+1e-6f);
  float sz=(float)GRIDC/(bbox[5]-bbox[2]+1e-6f);
  int cx=min(GRIDC-1,max(0,(int)((p.x-bbox[0])*sx)));
  int cy=min(GRIDC-1,max(0,(int)((p.y-bbox[1])*sy)));
  int cz=min(GRIDC-1,max(0,(int)((p.z-bbox[2])*sz)));
  int cell = morton12(cx,cy,cz);
  int pos = cellStart[cell] + atomicAdd(&cursor[cell],1);
  pfp[pos] = make_float4(p.x,p.y,p.z,__int_as_float(i));
}

// ---------------- MEGA: block 0 = FPS (prune + r1 skeleton); blocks 1..NW = transformer chain ----------------
__global__ __launch_bounds__(1024) void k_mega(
    const float4* __restrict__ pts4, const float4* __restrict__ pfp,
    const float* __restrict__ feat,
    const float* __restrict__ Wq, const float* __restrict__ Wk, const float* __restrict__ Wv,
    const float* __restrict__ Wp1, const float* __restrict__ gp, const float* __restrict__ bp,
    const float* __restrict__ Wp2, const float* __restrict__ Wa1, const float* __restrict__ Wa2,
    const float* __restrict__ ga1, const float* __restrict__ ba1,
    const float* __restrict__ ga2, const float* __restrict__ ba2, const float* __restrict__ b_a2,
    int* __restrict__ sidx,
    float* __restrict__ fq, float* __restrict__ fk, float* __restrict__ fv,
    int* __restrict__ kidx, float* __restrict__ y, float* __restrict__ yn,
    float* __restrict__ skip,
    float* __restrict__ psv, int* __restrict__ psi,
    float* __restrict__ stRel, float* __restrict__ stX, float* __restrict__ stX1,
    int* __restrict__ wctr)
{
  __shared__ __align__(16) char smem[32768];   // tile / wa1+wa2 / red (phase-unioned)
  __shared__ float rbv[16];
  __shared__ int   rbi[16];
  const int tid = threadIdx.x;

  if (blockIdx.x == 0) {
    // ======== FPS: r3-verified exact prune + r1-verified 2-barrier reduce ========
    #pragma clang fp contract(off)
    int t = tid;
    int base = t*16;
    float dm[16];
    float mnx=3e38f,mny=3e38f,mnz=3e38f,mxx=-3e38f,mxy=-3e38f,mxz=-3e38f;
    int minoid=0x7fffffff;
    #pragma unroll
    for (int m=0;m<16;m++){
      float4 p = pfp[base+m];
      mnx=fminf(mnx,p.x); mny=fminf(mny,p.y); mnz=fminf(mnz,p.z);
      mxx=fmaxf(mxx,p.x); mxy=fmaxf(mxy,p.y); mxz=fmaxf(mxz,p.z);
      minoid = min(minoid,__float_as_int(p.w));
      dm[m]=1e10f;
    }
    float cx=0.5f*(mnx+mxx), cy=0.5f*(mny+mxy), cz=0.5f*(mnz+mxz);
    float r2=0.f;
    #pragma unroll
    for (int m=0;m<16;m++){
      float4 p = pfp[base+m];
      float dx=p.x-cx,dy=p.y-cy,dz=p.z-cz;
      r2=fmaxf(r2,(dx*dx+dy*dy)+dz*dz);
    }
    float rS = sqrtf(r2)*1.00002f+1e-6f;
    float bvc=1e10f; int bic=minoid;   // cached (max own dmin, lowest-oid tie)
    int far=0;
    float4 f0=pts4[0];
    float fx=f0.x,fy=f0.y,fz=f0.z;
    for (int s=0;s<SP;s++){
      if (t==0) sidx[s]=far;
      float Dx=cx-fx,Dy=cy-fy,Dz=cz-fz;
      float D2=(Dx*Dx+Dy*Dy)+Dz*Dz;
      float tq=sqrtf(D2)-rS;
      bool skipc = (tq>0.f) && (tq*tq*0.999f >= bvc);  // exact: fmin no-op for all owned
      if (!skipc){
        float nbv=-1.f; int nbi=0x7fffffff;
        #pragma unroll
        for (int m=0;m<16;m++){
          float4 p = pfp[base+m];
          float dx=p.x-fx,dy=p.y-fy,dz=p.z-fz;
          float q0=dx*dx,q1=dy*dy,q2=dz*dz;
          float d=(q0+q1)+q2;              // reference assoc, no FMA
          float nd=fminf(dm[m],d);
          dm[m]=nd;
          int o=__float_as_int(p.w);
          bool g=(nd>nbv)||((nd==nbv)&&(o<nbi));
          nbv=g?nd:nbv; nbi=g?o:nbi;
        }
        bvc=nbv; bic=nbi;
      }
      float bv=bvc; int bi=bic;
      #pragma unroll
      for (int o=1;o<64;o<<=1){
        float ov=__shfl_xor(bv,o); int oi=__shfl_xor(bi,o);
        bool g=(ov>bv)||((ov==bv)&&(oi<bi));
        bv=g?ov:bv; bi=g?oi:bi;
      }
      __syncthreads();
      if ((t&63)==0){ rbv[t>>6]=bv; rbi[t>>6]=bi; }
      __syncthreads();
      float cv=rbv[t&15]; int ci=rbi[t&15];
      #pragma unroll
      for (int o=1;o<16;o<<=1){
        float ov=__shfl_xor(cv,o); int oi=__shfl_xor(ci,o);
        bool g=(ov>cv)||((ov==cv)&&(oi<ci));
        cv=g?ov:cv; ci=g?oi:ci;
      }
      far=ci;
      float4 fp=pts4[far];
      fx=fp.x; fy=fp.y; fz=fp.z;
    }
    return;
  }

  // ======== workers ========
  const int bid = blockIdx.x - 1;   // 0..NW-1
  const int c = tid & 63;

  // ---- P0: qkv ----
  {
    int rsl = tid>>6;
    for (int u = bid; u < NP/16; u += NW){
      int row = u*16 + rsl;
      const float* f = feat + row*CINCH;
      float aq=0.f, ak=0.f, av=0.f;
      #pragma unroll
      for (int k=0;k<CINCH;k++){
        float fe=f[k];
        aq=fmaf(fe,Wq[k*CO+c],aq); ak=fmaf(fe,Wk[k*CO+c],ak); av=fmaf(fe,Wv[k*CO+c],av);
      }
      fq[row*CO+c]=aq; fk[row*CO+c]=ak; fv[row*CO+c]=av;
    }
  }
  wbar(wctr, 1*NW);

  // ---- P1: knn16 partials, 8 parts x 2048 cands ----
  {
    float4* tile = (float4*)smem;
    int part = bid & 7, qb = bid >> 3;
    int q = qb*1024 + tid;
    int c0 = part*2048;
    for (int u=tid; u<2048; u+=1024) tile[u]=pts4[c0+u];
    __syncthreads();
    float4 tq = pts4[q];
    float qx=tq.x,qy=tq.y,qz=tq.z;
    float v[KK]; int id[KK];
    #pragma unroll
    for (int k=0;k<KK;k++){ v[k]=3.4e38f; id[k]=0x7fffffff; }
    for (int j=0;j<2048;j++){
      float4 cpt=tile[j];
      float dot = qx*cpt.x + qy*cpt.y + qz*cpt.z;
      float s = fmaf(-2.f,dot,cpt.w);
      if (s < v[KK-1]) {
        int gj = c0+j;
        #pragma unroll
        for (int k=KK-1;k>=1;--k){
          bool sh = s < v[k-1];
          bool pl = s < v[k];
          float nv = sh ? v[k-1] : (pl ? s  : v[k]);
          int   ni = sh ? id[k-1] : (pl ? gj : id[k]);
          v[k]=nv; id[k]=ni;
        }
        if (s < v[0]){ v[0]=s; id[0]=gj; }
      }
    }
    size_t o = ((size_t)q*8 + part)*KK;
    #pragma unroll
    for (int k=0;k<KK;k++){ psv[o+k]=v[k]; psi[o+k]=id[k]; }
  }
  wbar(wctr, 2*NW);

  // ---- P2: merge 8 sorted lists -> kidx ----
  {
    int q = bid*1024 + tid;
    if (q < NP) mergeQ<8>(psv + (size_t)q*8*KK, psi + (size_t)q*8*KK, kidx + q*KK);
  }
  wbar(wctr, 3*NW);

  // ---- P3: rel + stats ----
  {
    for (int r = bid*1024 + tid; r < NP*KK; r += NW*1024){
      int i = r>>4;
      int j = kidx[r];
      float4 pi=pts4[i], pj=pts4[j];
      float rx=pi.x-pj.x, ry=pi.y-pj.y, rz=pi.z-pj.z;
      float sv[3], sq[3];
      #pragma unroll
      for (int cc=0;cc<3;cc++){
        float yc = rx*Wp1[cc] + ry*Wp1[3+cc] + rz*Wp1[6+cc];
        y[r*3+cc]=yc; sv[cc]=yc; sq[cc]=yc*yc;
      }
      #pragma unroll
      for (int cc=0;cc<3;cc++){
        float a=sv[cc], b=sq[cc];
        #pragma unroll
        for (int o=32;o;o>>=1){ a+=__shfl_down(a,o); b+=__shfl_down(b,o); }
        if ((tid&63)==0){ atomicAdd(&stRel[cc],a); atomicAdd(&stRel[3+cc],b); }
      }
    }
  }
  wbar(wctr, 4*NW);

  // ---- P4: yn = relu(bn(y)) ----
  {
    const float invn = 1.f/(float)(NP*KK);
    for (int r = bid*1024 + tid; r < NP*KK; r += NW*1024){
      #pragma unroll
      for (int cc=0;cc<3;cc++){
        float m = stRel[cc]*invn;
        float var = stRel[3+cc]*invn - m*m;
        float rs = 1.f/sqrtf(var+1e-5f);
        float tt = (y[r*3+cc]-m)*rs;
        tt = fmaf(tt, gp[cc], bp[cc]);
        yn[r*3+cc] = fmaxf(tt,0.f);
      }
    }
  }
  wbar(wctr, 5*NW);

  // ---- P5: xstats ----
  {
    float* red = (float*)(smem + 16384);   // [2][16][64]
    int wv_ = tid>>6;
    float w0=Wp2[c], w1=Wp2[64+c], w2=Wp2[128+c];
    int row0 = (bid*16 + wv_)*128;
    float s=0.f,sq=0.f;
    for (int u=0;u<128;u++){
      int r=row0+u; int p=r>>4; int j=kidx[r];
      float y0=yn[r*3], y1=yn[r*3+1], y2=yn[r*3+2];
      float x = fq[p*CO+c]-fk[j*CO+c]+(y0*w0+y1*w1+y2*w2);
      s+=x; sq=fmaf(x,x,sq);
    }
    red[(0*16+wv_)*64+c]=s; red[(1*16+wv_)*64+c]=sq;
    __syncthreads();
    if (wv_==0){
      float a=0.f,b=0.f;
      #pragma unroll
      for (int u=0;u<16;u++){ a+=red[(0*16+u)*64+c]; b+=red[(1*16+u)*64+c]; }
      atomicAdd(&stX[c],a); atomicAdd(&stX[64+c],b);
    }
  }
  wbar(wctr, 6*NW);

  // ---- P6: x1stats ----
  {
    float* wa1 = (float*)smem;
    float* red = (float*)(smem + 16384);
    for (int u=tid; u<4096; u+=1024) wa1[u]=Wa1[u];
    __syncthreads();
    const float invn=1.f/(float)(NP*KK);
    float m1=stX[c]*invn; float vv=stX[64+c]*invn-m1*m1; float rs1=1.f/sqrtf(vv+1e-5f);
    float g1=ga1[c], bb1=ba1[c];
    float w0=Wp2[c],w1=Wp2[64+c],w2=Wp2[128+c];
    int wv_ = tid>>6;
    int row0 = (bid*16 + wv_)*128;
    float s=0.f,sq=0.f;
    for (int u=0;u<128;u++){
      int r=row0+u; int p=r>>4; int j=kidx[r];
      float y0=yn[r*3],y1=yn[r*3+1],y2=yn[r*3+2];
      float x = fq[p*CO+c]-fk[j*CO+c]+(y0*w0+y1*w1+y2*w2);
      float tt=(x-m1)*rs1; tt=fmaxf(fmaf(tt,g1,bb1),0.f);
      float x1 = waveGemm64(tt, wa1, c);
      s += x1; sq = fmaf(x1,x1,sq);
    }
    red[(0*16+wv_)*64+c]=s; red[(1*16+wv_)*64+c]=sq;
    __syncthreads();
    if (wv_==0){
      float a=0.f,b=0.f;
      #pragma unroll
      for (int u=0;u<16;u++){ a+=red[(0*16+u)*64+c]; b+=red[(1*16+u)*64+c]; }
      atomicAdd(&stX1[c],a); atomicAdd(&stX1[64+c],b);
    }
  }
  wbar(wctr, 7*NW);

  // ---- P7: attention -> skip ----
  {
    float* wa1 = (float*)smem;
    float* wa2 = (float*)(smem + 16384);
    for (int u=tid; u<4096; u+=1024){ wa1[u]=Wa1[u]; wa2[u]=Wa2[u]; }
    __syncthreads();
    const float invn = 1.f/(float)(NP*KK);
    float m1=stX[c]*invn;  float va=stX[64+c]*invn-m1*m1;  float rs1=1.f/sqrtf(va+1e-5f);
    float m2=stX1[c]*invn; float vb=stX1[64+c]*invn-m2*m2; float rs2=1.f/sqrtf(vb+1e-5f);
    float g1=ga1[c], bb1=ba1[c], g2=ga2[c], bb2=ba2[c], bc=b_a2[c];
    float w0=Wp2[c], w1=Wp2[64+c], w2=Wp2[128+c];
    int wv_ = tid>>6;
    for (int it=0; it<NP/(NW*16); it++){
      int p = (it*NW + bid)*16 + wv_;
      float fqv = fq[p*CO+c];
      float ex[16];
      #pragma unroll
      for (int k=0;k<16;k++){
        int r=p*16+k; int j=kidx[r];
        float y0=yn[r*3],y1=yn[r*3+1],y2=yn[r*3+2];
        float x = fqv - fk[j*CO+c] + (y0*w0+y1*w1+y2*w2);
        float t1 = (x-m1)*rs1; t1 = fmaxf(fmaf(t1,g1,bb1),0.f);
        float x1 = waveGemm64(t1, wa1, c);
        float t2 = (x1-m2)*rs2; t2 = fmaxf(fmaf(t2,g2,bb2),0.f);
        ex[k] = waveGemm64(t2, wa2, c) + bc;
      }
      float mx = ex[0];
      #pragma unroll
      for (int k=1;k<16;k++) mx = fmaxf(mx, ex[k]);
      float sum=0.f;
      #pragma unroll
      for (int k=0;k<16;k++){ ex[k]=expf(ex[k]-mx); sum+=ex[k]; }
      float acc=0.f;
      #pragma unroll
      for (int k=0;k<16;k++){
        int r=p*16+k; int j=kidx[r];
        float y0=yn[r*3],y1=yn[r*3+1],y2=yn[r*3+2];
        float rpe = y0*w0+y1*w1+y2*w2;
        acc = fmaf(ex[k], fv[j*CO+c]+rpe, acc);
      }
      skip[p*CO+c] = acc/sum;
    }
  }
}

// ---------------- gather sampled points ----------------
__global__ __launch_bounds__(256) void k_gather(const float4* __restrict__ pts4, const int* __restrict__ sidx,
    float4* __restrict__ spts4) {
  int q = blockIdx.x*256 + threadIdx.x;
  spts4[q] = pts4[sidx[q]];
}

// ---------------- KNN16 partial (standalone, for SP) ----------------
#define KTS 2048
__global__ __launch_bounds__(256,4) void k_knn16p(const float4* __restrict__ qp,
    const float4* __restrict__ cp, int clen,
    float* __restrict__ psv, int* __restrict__ psi) {
  __shared__ float4 tile[KTS];
  int q = blockIdx.x*256 + threadIdx.x;
  int part = blockIdx.y;
  int nspl = gridDim.y;
  int c0 = part*clen;
  float4 tq = qp[q];
  float qx=tq.x, qy=tq.y, qz=tq.z;
  float v[KK]; int id[KK];
  #pragma unroll
  for (int k=0;k<KK;k++){ v[k]=3.4e38f; id[k]=0x7fffffff; }
  for (int base=c0; base<c0+clen; base+=KTS){
    __syncthreads();
    for (int tt=threadIdx.x;tt<KTS;tt+=256) tile[tt]=cp[base+tt];
    __syncthreads();
    for (int j=0;j<KTS;j++){
      float4 cpt=tile[j];
      float dot = qx*cpt.x + qy*cpt.y + qz*cpt.z;
      float s = fmaf(-2.f,dot,cpt.w);
      if (s < v[KK-1]) {
        int gj = base+j;
        #pragma unroll
        for (int k=KK-1;k>=1;--k){
          bool sh = s < v[k-1];
          bool pl = s < v[k];
          float nv = sh ? v[k-1] : (pl ? s  : v[k]);
          int   ni = sh ? id[k-1] : (pl ? gj : id[k]);
          v[k]=nv; id[k]=ni;
        }
        if (s < v[0]){ v[0]=s; id[0]=gj; }
      }
    }
  }
  size_t o = ((size_t)q*nspl + part)*KK;
  #pragma unroll
  for (int k=0;k<KK;k++){ psv[o+k]=v[k]; psi[o+k]=id[k]; }
}

template<int NS>
__global__ __launch_bounds__(256,4) void k_merge(const float* __restrict__ psv,
    const int* __restrict__ psi, int* __restrict__ oidx) {
  int q = blockIdx.x*256 + threadIdx.x;
  mergeQ<NS>(psv + (size_t)q*NS*KK, psi + (size_t)q*NS*KK, oidx + q*KK);
}

// ---------------- TransitionDown pass 1 ----------------
__global__ __launch_bounds__(256) void k_d1(const float* __restrict__ skip, const int* __restrict__ idx2,
    const float* __restrict__ Wd1, float* __restrict__ t1, float* __restrict__ st) {
  __shared__ float wl[4096];
  __shared__ float red[2][4][64];
  for (int t=threadIdx.x;t<4096;t+=256) wl[t]=Wd1[t];
  int w=threadIdx.x>>6, c=threadIdx.x&63;
  __syncthreads();
  float s=0.f,sq=0.f;
  int row0 = blockIdx.x*64 + w*16;
  for (int t=0;t<16;t++){
    int r=row0+t; int src=idx2[r];
    float kf = skip[src*CO+c];
    float o = waveGemm64(kf, wl, c);
    t1[r*CO+c]=o; s+=o; sq=fmaf(o,o,sq);
  }
  red[0][w][c]=s; red[1][w][c]=sq;
  __syncthreads();
  if (w==0){
    float a=red[0][0][c]+red[0][1][c]+red[0][2][c]+red[0][3][c];
    float b=red[1][0][c]+red[1][1][c]+red[1][2][c]+red[1][3][c];
    atomicAdd(&st[c],a); atomicAdd(&st[64+c],b);
  }
}

// ---------------- TransitionDown pass 2 ----------------
__global__ __launch_bounds__(256) void k_d2(const float* __restrict__ t1in, const float* __restrict__ stin,
    const float* __restrict__ gd1, const float* __restrict__ bd1, const float* __restrict__ Wd2,
    float* __restrict__ t2, float* __restrict__ st) {
  __shared__ float wl[4096];
  __shared__ float red[2][4][64];
  for (int t=threadIdx.x;t<4096;t+=256) wl[t]=Wd2[t];
  int w=threadIdx.x>>6, c=threadIdx.x&63;
  const float invn = 1.f/(float)(SP*KK);
  float m=stin[c]*invn; float va=stin[64+c]*invn-m*m; float rs=1.f/sqrtf(va+1e-5f);
  float g=gd1[c], bb=bd1[c];
  __syncthreads();
  float s=0.f,sq=0.f;
  int row0 = blockIdx.x*64 + w*16;
  for (int t=0;t<16;t++){
    int r=row0+t;
    float h = (t1in[r*CO+c]-m)*rs; h = fmaxf(fmaf(h,g,bb),0.f);
    float o = waveGemm64(h, wl, c);
    t2[r*CO+c]=o; s+=o; sq=fmaf(o,o,sq);
  }
  red[0][w][c]=s; red[1][w][c]=sq;
  __syncthreads();
  if (w==0){
    float a=red[0][0][c]+red[0][1][c]+red[0][2][c]+red[0][3][c];
    float b=red[1][0][c]+red[1][1][c]+red[1][2][c]+red[1][3][c];
    atomicAdd(&st[c],a); atomicAdd(&st[64+c],b);
  }
}

// ---------------- down_f / df ----------------
__global__ __launch_bounds__(256) void k_downf(const float* __restrict__ t2, const float* __restrict__ stin,
    const float* __restrict__ gd2, const float* __restrict__ bd2, const float* __restrict__ Wdn,
    const float* __restrict__ bdn, float* __restrict__ df) {
  __shared__ float wl[4096];
  for (int t=threadIdx.x;t<4096;t+=256) wl[t]=Wdn[t];
  int w=threadIdx.x>>6, c=threadIdx.x&63;
  int srow = blockIdx.x*4 + w;
  const float invn = 1.f/(float)(SP*KK);
  float m=stin[c]*invn; float va=stin[64+c]*invn-m*m; float rs=1.f/sqrtf(va+1e-5f);
  float g=gd2[c], bb=bd2[c];
  __syncthreads();
  float mx=-3.4e38f;
  for (int k=0;k<16;k++){
    float h=(t2[(srow*16+k)*CO+c]-m)*rs; h=fmaxf(fmaf(h,g,bb),0.f);
    mx=fmaxf(mx,h);
  }
  float o = waveGemm64(mx, wl, c) + bdn[c];
  df[srow*CO+c]=o;
}

// ---------------- KNN k=3 ----------------
__global__ __launch_bounds__(256,4) void k_knn3(const float4* __restrict__ qp, const float4* __restrict__ cp,
    int* __restrict__ idx3, float* __restrict__ d3) {
  __shared__ float4 tile[2048];
  int q = blockIdx.x*256 + threadIdx.x;
  float4 Q = qp[q];
  float v0=3.4e38f,v1=3.4e38f,v2=3.4e38f;
  int i0=0x7fffffff,i1=0x7fffffff,i2=0x7fffffff;
  for (int base=0;base<SP;base+=2048){
    __syncthreads();
    for (int tt=threadIdx.x;tt<2048;tt+=256) tile[tt]=cp[base+tt];
    __syncthreads();
    for (int j=0;j<2048;j++){
      float4 cpt = tile[j];
      float dot = Q.x*cpt.x + Q.y*cpt.y + Q.z*cpt.z;
      float d = fmaf(-2.f, dot, Q.w) + cpt.w;
      if (d < v2){
        int gj = base+j;
        bool s2 = d < v1;
        bool s1 = d < v0;
        v2 = s2 ? v1 : d;  i2 = s2 ? i1 : gj;
        v1 = s2 ? (s1 ? v0 : d) : v1; i1 = s2 ? (s1 ? i0 : gj) : i1;
        v0 = s1 ? d : v0;  i0 = s1 ? gj : i0;
      }
    }
  }
  idx3[q*3]=i0; idx3[q*3+1]=i1; idx3[q*3+2]=i2;
  d3[q*3]=v0; d3[q*3+1]=v1; d3[q*3+2]=v2;
}

// ---------------- final output ----------------
__global__ __launch_bounds__(256) void k_out(const float* __restrict__ df, const int* __restrict__ idx3,
    const float* __restrict__ d3, const float* __restrict__ skip, const float* __restrict__ Wup,
    const float* __restrict__ bup, float* __restrict__ out) {
  __shared__ float wl[4096];
  for (int t=threadIdx.x;t<4096;t+=256) wl[t]=Wup[t];
  int w=threadIdx.x>>6, c=threadIdx.x&63;
  int i = blockIdx.x*4 + w;
  __syncthreads();
  int j0=idx3[i*3], j1=idx3[i*3+1], j2=idx3[i*3+2];
  float e0=d3[i*3], e1=d3[i*3+1], e2=d3[i*3+2];
  float r0=1.f/(e0+1e-8f), r1=1.f/(e1+1e-8f), r2=1.f/(e2+1e-8f);
  float sm=(r0+r1)+r2;
  float w0=r0/sm, w1=r1/sm, w2=r2/sm;
  float interp = (w0*df[j0*CO+c] + w1*df[j1*CO+c]) + w2*df[j2*CO+c];
  float sk = skip[i*CO+c];
  float up = waveGemm64(sk, wl, c);
  out[i*CO+c] = (interp + up) + bup[c];
}

// ---------------- launch ----------------
extern "C" void kernel_launch(void* const* d_in, const int* in_sizes, int n_in,
                              void* d_out, int out_size, void* d_ws, size_t ws_size,
                              hipStream_t stream) {
  (void)in_sizes; (void)n_in; (void)out_size; (void)ws_size;
  const float* points   = (const float*)d_in[0];
  const float* features = (const float*)d_in[1];
  const float* Wq  = (const float*)d_in[2];
  const float* Wk  = (const float*)d_in[3];
  const float* Wv  = (const float*)d_in[4];
  const float* ga1 = (const float*)d_in[5];
  const float* ba1 = (const float*)d_in[6];
  const float* Wa1 = (const float*)d_in[7];
  const float* ga2 = (const float*)d_in[8];
  const float* ba2 = (const float*)d_in[9];
  const float* Wa2 = (const float*)d_in[10];
  const float* b_a2= (const float*)d_in[11];
  const float* Wp1 = (const float*)d_in[12];
  const float* gp  = (const float*)d_in[13];
  const float* bp  = (const float*)d_in[14];
  const float* Wp2 = (const float*)d_in[15];
  const float* Wd1 = (const float*)d_in[16];
  const float* gd1 = (const float*)d_in[17];
  const float* bd1 = (const float*)d_in[18];
  const float* Wd2 = (const float*)d_in[19];
  const float* gd2 = (const float*)d_in[20];
  const float* bd2 = (const float*)d_in[21];
  const float* Wup = (const float*)d_in[22];
  const float* bup = (const float*)d_in[23];
  const float* Wdn = (const float*)d_in[24];
  const float* bdn = (const float*)d_in[25];
  float* out = (float*)d_out;

  char* wp = (char*)d_ws;
  auto carve = [&](size_t bytes)->char* { char* p = wp; wp += (bytes + 255) & ~(size_t)255; return p; };
  float4* pts4  = (float4*)carve((size_t)NP*16);
  float*  fq    = (float*) carve((size_t)NP*CO*4);
  float*  fk    = (float*) carve((size_t)NP*CO*4);
  float*  fv    = (float*) carve((size_t)NP*CO*4);
  int*    kidx  = (int*)   carve((size_t)NP*KK*4);
  float*  y     = (float*) carve((size_t)NP*KK*3*4);
  float*  yn    = (float*) carve((size_t)NP*KK*3*4);
  float*  skip  = (float*) carve((size_t)NP*CO*4);
  int*    sidx  = (int*)   carve((size_t)SP*4);
  float4* spts4 = (float4*)carve((size_t)SP*16);
  int*    idx2  = (int*)   carve((size_t)SP*KK*4);
  float*  t1    = (float*) carve((size_t)SP*KK*CO*4);   // 16MB: NP 8-way split bufs alias
  float*  t2    = (float*) carve((size_t)SP*KK*CO*4);   // 16MB: SP 8-way split bufs alias
  float*  df    = (float*) carve((size_t)SP*CO*4);
  int*    idx3  = (int*)   carve((size_t)NP*3*4);
  float*  d3    = (float*) carve((size_t)NP*3*4);
  float4* pfp   = (float4*)carve((size_t)NP*16);
  float*  bbox  = (float*) carve(256);
  int*    cellStart = (int*)carve((size_t)NCELLS*4);
  // zeroed region: stats(4096) + hist(16KB) + cursor(16KB), contiguous
  float*  stats = (float*) carve(4096);
  int*    hist  = (int*)   carve((size_t)NCELLS*4);
  int*    cursor= (int*)   carve((size_t)NCELLS*4);
  float* stRel = stats;        // 6 floats
  float* stX   = stats + 8;    // 128
  float* stX1  = stats + 136;  // 128
  float* stD1  = stats + 264;  // 128
  float* stD2  = stats + 392;  // 128
  int*   wctr  = (int*)(stats + 768);
  // NP knn split buffers alias t1 (8MB psv + 8MB psi = 16MB exactly)
  float* psvNP = t1;
  int*   psiNP = (int*)(t1 + (size_t)NP*8*KK);
  // SP knn split buffers alias t2
  float* psvSP = t2;
  int*   psiSP = (int*)(t2 + (size_t)SP*8*KK);

  hipMemsetAsync(stats, 0, 4096 + NCELLS*4*2, stream);

  k_pts4     <<<NP/256, 256, 0, stream>>>(points, pts4);
  k_bbox     <<<1, 1024, 0, stream>>>(pts4, bbox);
  k_cellhist <<<NP/256, 256, 0, stream>>>(pts4, bbox, hist);
  k_scan     <<<1, 1024, 0, stream>>>(hist, cellStart);
  k_scatter  <<<NP/256, 256, 0, stream>>>(pts4, bbox, cellStart, cursor, pfp);

  k_mega <<<1+NW, 1024, 0, stream>>>(pts4, pfp, features,
      Wq, Wk, Wv, Wp1, gp, bp, Wp2, Wa1, Wa2, ga1, ba1, ga2, ba2, b_a2,
      sidx, fq, fk, fv, kidx, y, yn, skip, psvNP, psiNP, stRel, stX, stX1, wctr);

  k_gather   <<<SP/256, 256, 0, stream>>>(pts4, sidx, spts4);
  k_knn16p   <<<dim3(SP/256,8), 256, 0, stream>>>(spts4, pts4, NP/8, psvSP, psiSP);
  k_merge<8> <<<SP/256, 256, 0, stream>>>(psvSP, psiSP, idx2);
  k_d1       <<<SP*KK/64, 256, 0, stream>>>(skip, idx2, Wd1, t1, stD1);
  k_d2       <<<SP*KK/64, 256, 0, stream>>>(t1, stD1, gd1, bd1, Wd2, t2, stD2);
  k_downf    <<<SP/4,   256, 0, stream>>>(t2, stD2, gd2, bd2, Wdn, bdn, df);
  k_knn3     <<<NP/256, 256, 0, stream>>>(pts4, spts4, idx3, d3);
  k_out      <<<NP/4,   256, 0, stream>>>(df, idx3, d3, skip, Wup, bup, out);
}

// Round 10
// 11235.697 us; speedup vs baseline: 1.2679x; 1.2679x over previous
//
#include <hip/hip_runtime.h>
#include <math.h>

#define NP 16384
#define SP 4096
#define CINCH 32
#define CO 64
#define KK 16
#define NW 192        // worker blocks in k_mega (grid = 1+NW = 193 <= 256 CUs)

// ---------------- helpers ----------------
__device__ __forceinline__ float waveGemm64(float xv, const float* __restrict__ wl, int c) {
  float a0=0.f,a1=0.f,a2=0.f,a3=0.f;
  #pragma unroll
  for (int k=0;k<64;k+=4){
    a0 = fmaf(__shfl(xv,k  ), wl[(k  )*CO+c], a0);
    a1 = fmaf(__shfl(xv,k+1), wl[(k+1)*CO+c], a1);
    a2 = fmaf(__shfl(xv,k+2), wl[(k+2)*CO+c], a2);
    a3 = fmaf(__shfl(xv,k+3), wl[(k+3)*CO+c], a3);
  }
  return (a0+a1)+(a2+a3);
}

template<int NS>
__device__ __forceinline__ void mergeQ(const float* __restrict__ pv, const int* __restrict__ pi,
                                       int* __restrict__ outp){
  int pos[NS]; float hv[NS]; int hi[NS];
  #pragma unroll
  for (int p=0;p<NS;p++){ pos[p]=0; hv[p]=pv[p*KK]; hi[p]=pi[p*KK]; }
  #pragma unroll
  for (int k=0;k<KK;k++){
    int best=0; float bv=hv[0]; int bi=hi[0];
    #pragma unroll
    for (int p=1;p<NS;p++){
      bool g=(hv[p]<bv)||((hv[p]==bv)&&(hi[p]<bi));
      if (g){ bv=hv[p]; bi=hi[p]; best=p; }
    }
    outp[k]=bi;
    #pragma unroll
    for (int p=0;p<NS;p++) if (best==p){
      pos[p]++;
      bool ok = pos[p]<KK;
      hv[p] = ok ? pv[p*KK+pos[p]] : 3.4e38f;
      hi[p] = ok ? pi[p*KK+pos[p]] : 0x7fffffff;
    }
  }
}

// worker barrier: arrive (RMW once) + read-only poll (no write storm)
__device__ __forceinline__ void wbar(int* ctr, int target){
  __syncthreads();
  if (threadIdx.x==0){
    __threadfence();
    atomicAdd(ctr,1);
    while (__hip_atomic_load(ctr, __ATOMIC_RELAXED, __HIP_MEMORY_SCOPE_AGENT) < target)
      __builtin_amdgcn_s_sleep(8);
    __threadfence();
  }
  __syncthreads();
}

// ---------------- pts4 + compact z ----------------
__global__ __launch_bounds__(256) void k_pts4(const float* __restrict__ pts,
    float4* __restrict__ pts4, float* __restrict__ pz) {
  int i = blockIdx.x*256 + threadIdx.x;
  float x = pts[3*i], y = pts[3*i+1], z = pts[3*i+2];
  pts4[i] = make_float4(x,y,z, x*x + y*y + z*z);
  pz[i] = z;
}

// ---------------- MEGA: block 0 = FPS (LDS-resident coords); blocks 1..NW = transformer ----------------
__global__ __launch_bounds__(1024) void k_mega(
    const float4* __restrict__ pts4, const float* __restrict__ pz,
    const float* __restrict__ feat,
    const float* __restrict__ Wq, const float* __restrict__ Wk, const float* __restrict__ Wv,
    const float* __restrict__ Wp1, const float* __restrict__ gp, const float* __restrict__ bp,
    const float* __restrict__ Wp2, const float* __restrict__ Wa1, const float* __restrict__ Wa2,
    const float* __restrict__ ga1, const float* __restrict__ ba1,
    const float* __restrict__ ga2, const float* __restrict__ ba2, const float* __restrict__ b_a2,
    int* __restrict__ sidx,
    float* __restrict__ fq, float* __restrict__ fk, float* __restrict__ fv,
    int* __restrict__ kidx, float* __restrict__ y, float* __restrict__ yn,
    float* __restrict__ skip,
    float* __restrict__ psv, int* __restrict__ psi,
    float* __restrict__ stRel, float* __restrict__ stX, float* __restrict__ stX1,
    int* __restrict__ wctr)
{
  // union LDS: FPS = xy[16384] float2 (128KiB) + rbv/rbi; workers use first 32KB
  __shared__ __align__(16) char smem[131200];
  const int tid = threadIdx.x;

  if (blockIdx.x == 0) {
    // ======== FPS v10: x,y in LDS; z,dm in regs; r1's exact 2-barrier reduce ========
    #pragma clang fp contract(off)
    float2* xy = (float2*)smem;
    float*  rbv = (float*)(smem + 131072);
    int*    rbi = (int*)  (smem + 131072 + 64);
    int t = tid;
    float z[16], dm[16];
    #pragma unroll
    for (int m=0;m<16;m++){
      float4 p = pts4[t*16+m];
      xy[m*1024+t] = make_float2(p.x, p.y);
      z[m] = pz[t*16+m];
      dm[m] = 1e10f;
    }
    __syncthreads();
    int far = 0;
    float4 f0 = pts4[0];
    float fx=f0.x, fy=f0.y, fz=f0.z;
    for (int s=0;s<SP;s++){
      if (t==0) sidx[s]=far;
      float bv=-1.f; int bi=0;
      #pragma unroll
      for (int m=0;m<16;m++){
        float2 p = xy[m*1024+t];
        float dx=p.x-fx, dy=p.y-fy, dz=z[m]-fz;
        float q0=dx*dx, q1=dy*dy, q2=dz*dz;
        float d=(q0+q1)+q2;                 // matches reference ((d0+d1)+d2), no FMA
        float nd=fminf(dm[m],d);
        dm[m]=nd;
        bool g = nd>bv;                     // strict: ties keep lower index
        bv = g?nd:bv;
        bi = g?(t*16+m):bi;
      }
      #pragma unroll
      for (int o=1;o<64;o<<=1){
        float ov=__shfl_xor(bv,o); int oi=__shfl_xor(bi,o);
        bool g = (ov>bv)||((ov==bv)&&(oi<bi));
        bv=g?ov:bv; bi=g?oi:bi;
      }
      __syncthreads();
      if ((t&63)==0){ rbv[t>>6]=bv; rbi[t>>6]=bi; }
      __syncthreads();
      float cv=rbv[t&15]; int ci=rbi[t&15];
      #pragma unroll
      for (int o=1;o<16;o<<=1){
        float ov=__shfl_xor(cv,o); int oi=__shfl_xor(ci,o);
        bool g=(ov>cv)||((ov==cv)&&(oi<ci));
        cv=g?ov:cv; ci=g?oi:ci;
      }
      far = ci;
      float4 fp = pts4[far];
      fx=fp.x; fy=fp.y; fz=fp.z;
    }
    return;
  }

  // ======== workers ========
  const int bid = blockIdx.x - 1;   // 0..NW-1
  const int c = tid & 63;
  const int wv_ = tid >> 6;

  // ---- P0: qkv ----
  for (int u = bid; u < NP/16; u += NW){
    int row = u*16 + wv_;
    const float* f = feat + row*CINCH;
    float aq=0.f, ak=0.f, av=0.f;
    #pragma unroll
    for (int k=0;k<CINCH;k++){
      float fe=f[k];
      aq=fmaf(fe,Wq[k*CO+c],aq); ak=fmaf(fe,Wk[k*CO+c],ak); av=fmaf(fe,Wv[k*CO+c],av);
    }
    fq[row*CO+c]=aq; fk[row*CO+c]=ak; fv[row*CO+c]=av;
  }
  wbar(wctr, 1*NW);

  // ---- P1: knn16 partials, 16 parts x 1024 cands x 16 query-blocks ----
  {
    float4* tile = (float4*)smem;   // 16KB
    for (int u = bid; u < 256; u += NW){
      int qb = u>>4, part = u&15;
      int q = qb*1024 + tid;
      int c0 = part*1024;
      __syncthreads();
      tile[tid] = pts4[c0+tid];
      __syncthreads();
      float4 tq = pts4[q];
      float qx=tq.x,qy=tq.y,qz=tq.z;
      float v[KK]; int id[KK];
      #pragma unroll
      for (int k=0;k<KK;k++){ v[k]=3.4e38f; id[k]=0x7fffffff; }
      for (int j=0;j<1024;j++){
        float4 cpt=tile[j];
        float dot = qx*cpt.x + qy*cpt.y + qz*cpt.z;
        float s = fmaf(-2.f,dot,cpt.w);
        if (s < v[KK-1]) {
          int gj = c0+j;
          #pragma unroll
          for (int k=KK-1;k>=1;--k){
            bool sh = s < v[k-1];
            bool pl = s < v[k];
            float nv = sh ? v[k-1] : (pl ? s  : v[k]);
            int   ni = sh ? id[k-1] : (pl ? gj : id[k]);
            v[k]=nv; id[k]=ni;
          }
          if (s < v[0]){ v[0]=s; id[0]=gj; }
        }
      }
      size_t o = ((size_t)q*16 + part)*KK;
      #pragma unroll
      for (int k=0;k<KK;k++){ psv[o+k]=v[k]; psi[o+k]=id[k]; }
    }
  }
  wbar(wctr, 2*NW);

  // ---- P2: merge 16 sorted lists -> kidx ----
  {
    int q = bid*1024 + tid;
    if (q < NP) mergeQ<16>(psv + (size_t)q*16*KK, psi + (size_t)q*16*KK, kidx + q*KK);
  }
  wbar(wctr, 3*NW);

  // ---- P3: rel + stats ----
  for (int r = bid*1024 + tid; r < NP*KK; r += NW*1024){
    int i = r>>4;
    int j = kidx[r];
    float4 pi=pts4[i], pj=pts4[j];
    float rx=pi.x-pj.x, ry=pi.y-pj.y, rz=pi.z-pj.z;
    float sv[3], sq[3];
    #pragma unroll
    for (int cc=0;cc<3;cc++){
      float yc = rx*Wp1[cc] + ry*Wp1[3+cc] + rz*Wp1[6+cc];
      y[r*3+cc]=yc; sv[cc]=yc; sq[cc]=yc*yc;
    }
    #pragma unroll
    for (int cc=0;cc<3;cc++){
      float a=sv[cc], b=sq[cc];
      #pragma unroll
      for (int o=32;o;o>>=1){ a+=__shfl_down(a,o); b+=__shfl_down(b,o); }
      if ((tid&63)==0){ atomicAdd(&stRel[cc],a); atomicAdd(&stRel[3+cc],b); }
    }
  }
  wbar(wctr, 4*NW);

  // ---- P4: yn = relu(bn(y)) ----
  {
    const float invn = 1.f/(float)(NP*KK);
    for (int r = bid*1024 + tid; r < NP*KK; r += NW*1024){
      #pragma unroll
      for (int cc=0;cc<3;cc++){
        float m = stRel[cc]*invn;
        float var = stRel[3+cc]*invn - m*m;
        float rs = 1.f/sqrtf(var+1e-5f);
        float tt = (y[r*3+cc]-m)*rs;
        tt = fmaf(tt, gp[cc], bp[cc]);
        yn[r*3+cc] = fmaxf(tt,0.f);
      }
    }
  }
  wbar(wctr, 5*NW);

  // ---- P5: xstats (256 units x 16 waves x 64 rows) ----
  {
    float* red = (float*)(smem + 16384);   // [2][16][64]
    float w0=Wp2[c], w1=Wp2[64+c], w2=Wp2[128+c];
    float s=0.f,sq=0.f;
    for (int u = bid; u < 256; u += NW){
      int row0 = (u*16 + wv_)*64;
      for (int q2=0;q2<64;q2++){
        int r=row0+q2; int p=r>>4; int j=kidx[r];
        float y0=yn[r*3], y1=yn[r*3+1], y2=yn[r*3+2];
        float x = fq[p*CO+c]-fk[j*CO+c]+(y0*w0+y1*w1+y2*w2);
        s+=x; sq=fmaf(x,x,sq);
      }
    }
    red[(0*16+wv_)*64+c]=s; red[(1*16+wv_)*64+c]=sq;
    __syncthreads();
    if (wv_==0){
      float a=0.f,b=0.f;
      #pragma unroll
      for (int u=0;u<16;u++){ a+=red[(0*16+u)*64+c]; b+=red[(1*16+u)*64+c]; }
      atomicAdd(&stX[c],a); atomicAdd(&stX[64+c],b);
    }
  }
  wbar(wctr, 6*NW);

  // ---- P6: x1stats ----
  {
    float* wa1 = (float*)smem;
    float* red = (float*)(smem + 16384);
    for (int u=tid; u<4096; u+=1024) wa1[u]=Wa1[u];
    __syncthreads();
    const float invn=1.f/(float)(NP*KK);
    float m1=stX[c]*invn; float vv=stX[64+c]*invn-m1*m1; float rs1=1.f/sqrtf(vv+1e-5f);
    float g1=ga1[c], bb1=ba1[c];
    float w0=Wp2[c],w1=Wp2[64+c],w2=Wp2[128+c];
    float s=0.f,sq=0.f;
    for (int u = bid; u < 256; u += NW){
      int row0 = (u*16 + wv_)*64;
      for (int q2=0;q2<64;q2++){
        int r=row0+q2; int p=r>>4; int j=kidx[r];
        float y0=yn[r*3],y1=yn[r*3+1],y2=yn[r*3+2];
        float x = fq[p*CO+c]-fk[j*CO+c]+(y0*w0+y1*w1+y2*w2);
        float tt=(x-m1)*rs1; tt=fmaxf(fmaf(tt,g1,bb1),0.f);
        float x1 = waveGemm64(tt, wa1, c);
        s += x1; sq = fmaf(x1,x1,sq);
      }
    }
    red[(0*16+wv_)*64+c]=s; red[(1*16+wv_)*64+c]=sq;
    __syncthreads();
    if (wv_==0){
      float a=0.f,b=0.f;
      #pragma unroll
      for (int u=0;u<16;u++){ a+=red[(0*16+u)*64+c]; b+=red[(1*16+u)*64+c]; }
      atomicAdd(&stX1[c],a); atomicAdd(&stX1[64+c],b);
    }
  }
  wbar(wctr, 7*NW);

  // ---- P7: attention -> skip ----
  {
    float* wa1 = (float*)smem;
    float* wa2 = (float*)(smem + 16384);
    __syncthreads();
    for (int u=tid; u<4096; u+=1024){ wa1[u]=Wa1[u]; wa2[u]=Wa2[u]; }
    __syncthreads();
    const float invn = 1.f/(float)(NP*KK);
    float m1=stX[c]*invn;  float va=stX[64+c]*invn-m1*m1;  float rs1=1.f/sqrtf(va+1e-5f);
    float m2=stX1[c]*invn; float vb=stX1[64+c]*invn-m2*m2; float rs2=1.f/sqrtf(vb+1e-5f);
    float g1=ga1[c], bb1=ba1[c], g2=ga2[c], bb2=ba2[c], bc=b_a2[c];
    float w0=Wp2[c], w1=Wp2[64+c], w2=Wp2[128+c];
    for (int u = bid; u < NP/16; u += NW){
      int p = u*16 + wv_;
      float fqv = fq[p*CO+c];
      float ex[16];
      #pragma unroll
      for (int k=0;k<16;k++){
        int r=p*16+k; int j=kidx[r];
        float y0=yn[r*3],y1=yn[r*3+1],y2=yn[r*3+2];
        float x = fqv - fk[j*CO+c] + (y0*w0+y1*w1+y2*w2);
        float t1 = (x-m1)*rs1; t1 = fmaxf(fmaf(t1,g1,bb1),0.f);
        float x1 = waveGemm64(t1, wa1, c);
        float t2 = (x1-m2)*rs2; t2 = fmaxf(fmaf(t2,g2,bb2),0.f);
        ex[k] = waveGemm64(t2, wa2, c) + bc;
      }
      float mx = ex[0];
      #pragma unroll
      for (int k=1;k<16;k++) mx = fmaxf(mx, ex[k]);
      float sum=0.f;
      #pragma unroll
      for (int k=0;k<16;k++){ ex[k]=expf(ex[k]-mx); sum+=ex[k]; }
      float acc=0.f;
      #pragma unroll
      for (int k=0;k<16;k++){
        int r=p*16+k; int j=kidx[r];
        float y0=yn[r*3],y1=yn[r*3+1],y2=yn[r*3+2];
        float rpe = y0*w0+y1*w1+y2*w2;
        acc = fmaf(ex[k], fv[j*CO+c]+rpe, acc);
      }
      skip[p*CO+c] = acc/sum;
    }
  }
}

// ---------------- gather sampled points ----------------
__global__ __launch_bounds__(256) void k_gather(const float4* __restrict__ pts4, const int* __restrict__ sidx,
    float4* __restrict__ spts4) {
  int q = blockIdx.x*256 + threadIdx.x;
  spts4[q] = pts4[sidx[q]];
}

// ---------------- KNN16 partial (standalone, for SP) ----------------
#define KTS 2048
__global__ __launch_bounds__(256,4) void k_knn16p(const float4* __restrict__ qp,
    const float4* __restrict__ cp, int clen,
    float* __restrict__ psv, int* __restrict__ psi) {
  __shared__ float4 tile[KTS];
  int q = blockIdx.x*256 + threadIdx.x;
  int part = blockIdx.y;
  int nspl = gridDim.y;
  int c0 = part*clen;
  float4 tq = qp[q];
  float qx=tq.x, qy=tq.y, qz=tq.z;
  float v[KK]; int id[KK];
  #pragma unroll
  for (int k=0;k<KK;k++){ v[k]=3.4e38f; id[k]=0x7fffffff; }
  for (int base=c0; base<c0+clen; base+=KTS){
    __syncthreads();
    for (int tt=threadIdx.x;tt<KTS;tt+=256) tile[tt]=cp[base+tt];
    __syncthreads();
    for (int j=0;j<KTS;j++){
      float4 cpt=tile[j];
      float dot = qx*cpt.x + qy*cpt.y + qz*cpt.z;
      float s = fmaf(-2.f,dot,cpt.w);
      if (s < v[KK-1]) {
        int gj = base+j;
        #pragma unroll
        for (int k=KK-1;k>=1;--k){
          bool sh = s < v[k-1];
          bool pl = s < v[k];
          float nv = sh ? v[k-1] : (pl ? s  : v[k]);
          int   ni = sh ? id[k-1] : (pl ? gj : id[k]);
          v[k]=nv; id[k]=ni;
        }
        if (s < v[0]){ v[0]=s; id[0]=gj; }
      }
    }
  }
  size_t o = ((size_t)q*nspl + part)*KK;
  #pragma unroll
  for (int k=0;k<KK;k++){ psv[o+k]=v[k]; psi[o+k]=id[k]; }
}

template<int NS>
__global__ __launch_bounds__(256,4) void k_merge(const float* __restrict__ psv,
    const int* __restrict__ psi, int* __restrict__ oidx) {
  int q = blockIdx.x*256 + threadIdx.x;
  mergeQ<NS>(psv + (size_t)q*NS*KK, psi + (size_t)q*NS*KK, oidx + q*KK);
}

// ---------------- TransitionDown pass 1 ----------------
__global__ __launch_bounds__(256) void k_d1(const float* __restrict__ skip, const int* __restrict__ idx2,
    const float* __restrict__ Wd1, float* __restrict__ t1, float* __restrict__ st) {
  __shared__ float wl[4096];
  __shared__ float red[2][4][64];
  for (int t=threadIdx.x;t<4096;t+=256) wl[t]=Wd1[t];
  int w=threadIdx.x>>6, c=threadIdx.x&63;
  __syncthreads();
  float s=0.f,sq=0.f;
  int row0 = blockIdx.x*64 + w*16;
  for (int t=0;t<16;t++){
    int r=row0+t; int src=idx2[r];
    float kf = skip[src*CO+c];
    float o = waveGemm64(kf, wl, c);
    t1[r*CO+c]=o; s+=o; sq=fmaf(o,o,sq);
  }
  red[0][w][c]=s; red[1][w][c]=sq;
  __syncthreads();
  if (w==0){
    float a=red[0][0][c]+red[0][1][c]+red[0][2][c]+red[0][3][c];
    float b=red[1][0][c]+red[1][1][c]+red[1][2][c]+red[1][3][c];
    atomicAdd(&st[c],a); atomicAdd(&st[64+c],b);
  }
}

// ---------------- TransitionDown pass 2 ----------------
__global__ __launch_bounds__(256) void k_d2(const float* __restrict__ t1in, const float* __restrict__ stin,
    const float* __restrict__ gd1, const float* __restrict__ bd1, const float* __restrict__ Wd2,
    float* __restrict__ t2, float* __restrict__ st) {
  __shared__ float wl[4096];
  __shared__ float red[2][4][64];
  for (int t=threadIdx.x;t<4096;t+=256) wl[t]=Wd2[t];
  int w=threadIdx.x>>6, c=threadIdx.x&63;
  const float invn = 1.f/(float)(SP*KK);
  float m=stin[c]*invn; float va=stin[64+c]*invn-m*m; float rs=1.f/sqrtf(va+1e-5f);
  float g=gd1[c], bb=bd1[c];
  __syncthreads();
  float s=0.f,sq=0.f;
  int row0 = blockIdx.x*64 + w*16;
  for (int t=0;t<16;t++){
    int r=row0+t;
    float h = (t1in[r*CO+c]-m)*rs; h = fmaxf(fmaf(h,g,bb),0.f);
    float o = waveGemm64(h, wl, c);
    t2[r*CO+c]=o; s+=o; sq=fmaf(o,o,sq);
  }
  red[0][w][c]=s; red[1][w][c]=sq;
  __syncthreads();
  if (w==0){
    float a=red[0][0][c]+red[0][1][c]+red[0][2][c]+red[0][3][c];
    float b=red[1][0][c]+red[1][1][c]+red[1][2][c]+red[1][3][c];
    atomicAdd(&st[c],a); atomicAdd(&st[64+c],b);
  }
}

// ---------------- down_f / df ----------------
__global__ __launch_bounds__(256) void k_downf(const float* __restrict__ t2, const float* __restrict__ stin,
    const float* __restrict__ gd2, const float* __restrict__ bd2, const float* __restrict__ Wdn,
    const float* __restrict__ bdn, float* __restrict__ df) {
  __shared__ float wl[4096];
  for (int t=threadIdx.x;t<4096;t+=256) wl[t]=Wdn[t];
  int w=threadIdx.x>>6, c=threadIdx.x&63;
  int srow = blockIdx.x*4 + w;
  const float invn = 1.f/(float)(SP*KK);
  float m=stin[c]*invn; float va=stin[64+c]*invn-m*m; float rs=1.f/sqrtf(va+1e-5f);
  float g=gd2[c], bb=bd2[c];
  __syncthreads();
  float mx=-3.4e38f;
  for (int k=0;k<16;k++){
    float h=(t2[(srow*16+k)*CO+c]-m)*rs; h=fmaxf(fmaf(h,g,bb),0.f);
    mx=fmaxf(mx,h);
  }
  float o = waveGemm64(mx, wl, c) + bdn[c];
  df[srow*CO+c]=o;
}

// ---------------- KNN k=3 ----------------
__global__ __launch_bounds__(256,4) void k_knn3(const float4* __restrict__ qp, const float4* __restrict__ cp,
    int* __restrict__ idx3, float* __restrict__ d3) {
  __shared__ float4 tile[2048];
  int q = blockIdx.x*256 + threadIdx.x;
  float4 Q = qp[q];
  float v0=3.4e38f,v1=3.4e38f,v2=3.4e38f;
  int i0=0x7fffffff,i1=0x7fffffff,i2=0x7fffffff;
  for (int base=0;base<SP;base+=2048){
    __syncthreads();
    for (int tt=threadIdx.x;tt<2048;tt+=256) tile[tt]=cp[base+tt];
    __syncthreads();
    for (int j=0;j<2048;j++){
      float4 cpt = tile[j];
      float dot = Q.x*cpt.x + Q.y*cpt.y + Q.z*cpt.z;
      float d = fmaf(-2.f, dot, Q.w) + cpt.w;
      if (d < v2){
        int gj = base+j;
        bool s2 = d < v1;
        bool s1 = d < v0;
        v2 = s2 ? v1 : d;  i2 = s2 ? i1 : gj;
        v1 = s2 ? (s1 ? v0 : d) : v1; i1 = s2 ? (s1 ? i0 : gj) : i1;
        v0 = s1 ? d : v0;  i0 = s1 ? gj : i0;
      }
    }
  }
  idx3[q*3]=i0; idx3[q*3+1]=i1; idx3[q*3+2]=i2;
  d3[q*3]=v0; d3[q*3+1]=v1; d3[q*3+2]=v2;
}

// ---------------- final output ----------------
__global__ __launch_bounds__(256) void k_out(const float* __restrict__ df, const int* __restrict__ idx3,
    const float* __restrict__ d3, const float* __restrict__ skip, const float* __restrict__ Wup,
    const float* __restrict__ bup, float* __restrict__ out) {
  __shared__ float wl[4096];
  for (int t=threadIdx.x;t<4096;t+=256) wl[t]=Wup[t];
  int w=threadIdx.x>>6, c=threadIdx.x&63;
  int i = blockIdx.x*4 + w;
  __syncthreads();
  int j0=idx3[i*3], j1=idx3[i*3+1], j2=idx3[i*3+2];
  float e0=d3[i*3], e1=d3[i*3+1], e2=d3[i*3+2];
  float r0=1.f/(e0+1e-8f), r1=1.f/(e1+1e-8f), r2=1.f/(e2+1e-8f);
  float sm=(r0+r1)+r2;
  float w0=r0/sm, w1=r1/sm, w2=r2/sm;
  float interp = (w0*df[j0*CO+c] + w1*df[j1*CO+c]) + w2*df[j2*CO+c];
  float sk = skip[i*CO+c];
  float up = waveGemm64(sk, wl, c);
  out[i*CO+c] = (interp + up) + bup[c];
}

// ---------------- launch ----------------
extern "C" void kernel_launch(void* const* d_in, const int* in_sizes, int n_in,
                              void* d_out, int out_size, void* d_ws, size_t ws_size,
                              hipStream_t stream) {
  (void)in_sizes; (void)n_in; (void)out_size; (void)ws_size;
  const float* points   = (const float*)d_in[0];
  const float* features = (const float*)d_in[1];
  const float* Wq  = (const float*)d_in[2];
  const float* Wk  = (const float*)d_in[3];
  const float* Wv  = (const float*)d_in[4];
  const float* ga1 = (const float*)d_in[5];
  const float* ba1 = (const float*)d_in[6];
  const float* Wa1 = (const float*)d_in[7];
  const float* ga2 = (const float*)d_in[8];
  const float* ba2 = (const float*)d_in[9];
  const float* Wa2 = (const float*)d_in[10];
  const float* b_a2= (const float*)d_in[11];
  const float* Wp1 = (const float*)d_in[12];
  const float* gp  = (const float*)d_in[13];
  const float* bp  = (const float*)d_in[14];
  const float* Wp2 = (const float*)d_in[15];
  const float* Wd1 = (const float*)d_in[16];
  const float* gd1 = (const float*)d_in[17];
  const float* bd1 = (const float*)d_in[18];
  const float* Wd2 = (const float*)d_in[19];
  const float* gd2 = (const float*)d_in[20];
  const float* bd2 = (const float*)d_in[21];
  const float* Wup = (const float*)d_in[22];
  const float* bup = (const float*)d_in[23];
  const float* Wdn = (const float*)d_in[24];
  const float* bdn = (const float*)d_in[25];
  float* out = (float*)d_out;

  char* wp = (char*)d_ws;
  auto carve = [&](size_t bytes)->char* { char* p = wp; wp += (bytes + 255) & ~(size_t)255; return p; };
  float4* pts4  = (float4*)carve((size_t)NP*16);
  float*  pz    = (float*) carve((size_t)NP*4);
  float*  fq    = (float*) carve((size_t)NP*CO*4);
  float*  fk    = (float*) carve((size_t)NP*CO*4);
  float*  fv    = (float*) carve((size_t)NP*CO*4);
  int*    kidx  = (int*)   carve((size_t)NP*KK*4);
  float*  y     = (float*) carve((size_t)NP*KK*3*4);
  float*  yn    = (float*) carve((size_t)NP*KK*3*4);
  float*  skip  = (float*) carve((size_t)NP*CO*4);
  int*    sidx  = (int*)   carve((size_t)SP*4);
  float4* spts4 = (float4*)carve((size_t)SP*16);
  int*    idx2  = (int*)   carve((size_t)SP*KK*4);
  float*  t1    = (float*) carve((size_t)SP*KK*CO*4);   // 16MB: NP psv (16 parts) aliases
  float*  t2    = (float*) carve((size_t)SP*KK*CO*4);   // 16MB: NP psi aliases; later SP bufs
  float*  df    = (float*) carve((size_t)SP*CO*4);
  int*    idx3  = (int*)   carve((size_t)NP*3*4);
  float*  d3    = (float*) carve((size_t)NP*3*4);
  float*  stats = (float*) carve(4096);                 // zeroed each launch
  float* stRel = stats;        // 6 floats
  float* stX   = stats + 8;    // 128
  float* stX1  = stats + 136;  // 128
  float* stD1  = stats + 264;  // 128
  float* stD2  = stats + 392;  // 128
  int*   wctr  = (int*)(stats + 768);
  // NP knn split buffers: psv = t1 (16384*16*16*4 = 16MB), psi = t2 (16MB)
  float* psvNP = t1;
  int*   psiNP = (int*)t2;
  // SP knn split buffers live in t2 after mega consumed psiNP (2MB + 2MB)
  float* psvSP = t2;
  int*   psiSP = (int*)(t2 + (size_t)SP*8*KK);

  hipMemsetAsync(stats, 0, 4096, stream);

  k_pts4 <<<NP/256, 256, 0, stream>>>(points, pts4, pz);

  k_mega <<<1+NW, 1024, 0, stream>>>(pts4, pz, features,
      Wq, Wk, Wv, Wp1, gp, bp, Wp2, Wa1, Wa2, ga1, ba1, ga2, ba2, b_a2,
      sidx, fq, fk, fv, kidx, y, yn, skip, psvNP, psiNP, stRel, stX, stX1, wctr);

  k_gather   <<<SP/256, 256, 0, stream>>>(pts4, sidx, spts4);
  k_knn16p   <<<dim3(SP/256,8), 256, 0, stream>>>(spts4, pts4, NP/8, psvSP, psiSP);
  k_merge<8> <<<SP/256, 256, 0, stream>>>(psvSP, psiSP, idx2);
  k_d1       <<<SP*KK/64, 256, 0, stream>>>(skip, idx2, Wd1, t1, stD1);
  k_d2       <<<SP*KK/64, 256, 0, stream>>>(t1, stD1, gd1, bd1, Wd2, t2, stD2);
  k_downf    <<<SP/4,   256, 0, stream>>>(t2, stD2, gd2, bd2, Wdn, bdn, df);
  k_knn3     <<<NP/256, 256, 0, stream>>>(pts4, spts4, idx3, d3);
  k_out      <<<NP/4,   256, 0, stream>>>(df, idx3, d3, skip, Wup, bup, out);
}

// Round 11
// 10515.031 us; speedup vs baseline: 1.3548x; 1.0685x over previous
//
#include <hip/hip_runtime.h>
#include <math.h>

#define NP 16384
#define SP 4096
#define CINCH 32
#define CO 64
#define KK 16
#define NW 192        // worker blocks in k_mega (grid = 1+NW = 193)

// ---------------- helpers ----------------
__device__ __forceinline__ float waveGemm64(float xv, const float* __restrict__ wl, int c) {
  float a0=0.f,a1=0.f,a2=0.f,a3=0.f;
  #pragma unroll
  for (int k=0;k<64;k+=4){
    a0 = fmaf(__shfl(xv,k  ), wl[(k  )*CO+c], a0);
    a1 = fmaf(__shfl(xv,k+1), wl[(k+1)*CO+c], a1);
    a2 = fmaf(__shfl(xv,k+2), wl[(k+2)*CO+c], a2);
    a3 = fmaf(__shfl(xv,k+3), wl[(k+3)*CO+c], a3);
  }
  return (a0+a1)+(a2+a3);
}

template<int NS>
__device__ __forceinline__ void mergeQ(const float* __restrict__ pv, const int* __restrict__ pi,
                                       int* __restrict__ outp){
  int pos[NS]; float hv[NS]; int hi[NS];
  #pragma unroll
  for (int p=0;p<NS;p++){ pos[p]=0; hv[p]=pv[p*KK]; hi[p]=pi[p*KK]; }
  #pragma unroll
  for (int k=0;k<KK;k++){
    int best=0; float bv=hv[0]; int bi=hi[0];
    #pragma unroll
    for (int p=1;p<NS;p++){
      bool g=(hv[p]<bv)||((hv[p]==bv)&&(hi[p]<bi));
      if (g){ bv=hv[p]; bi=hi[p]; best=p; }
    }
    outp[k]=bi;
    #pragma unroll
    for (int p=0;p<NS;p++) if (best==p){
      pos[p]++;
      bool ok = pos[p]<KK;
      hv[p] = ok ? pv[p*KK+pos[p]] : 3.4e38f;
      hi[p] = ok ? pi[p*KK+pos[p]] : 0x7fffffff;
    }
  }
}

// worker barrier: arrive (one RMW) + read-only poll
__device__ __forceinline__ void wbar(int* ctr, int target){
  __syncthreads();
  if (threadIdx.x==0){
    __threadfence();
    atomicAdd(ctr,1);
    while (__hip_atomic_load(ctr, __ATOMIC_RELAXED, __HIP_MEMORY_SCOPE_AGENT) < target)
      __builtin_amdgcn_s_sleep(8);
    __threadfence();
  }
  __syncthreads();
}

// ---------------- pts4 ----------------
__global__ __launch_bounds__(256) void k_pts4(const float* __restrict__ pts, float4* __restrict__ pts4) {
  int i = blockIdx.x*256 + threadIdx.x;
  float x = pts[3*i], y = pts[3*i+1], z = pts[3*i+2];
  pts4[i] = make_float4(x,y,z, x*x + y*y + z*z);
}

// ---------------- MEGA (512 thr): block 0 = FPS; blocks 1..NW = transformer ----------------
// FPS v11: 512 thr x 32 pts. x,y in LDS (128KB); z[32] asm-pinned regs; dm[32]
// regs (512-thr blocks are the one config the RA allocates arrays for - r4:
// VGPR=88). r1's exact lean reduce (butterfly + 2 barriers, 8-entry stage).
__global__ __launch_bounds__(512,2) void k_mega(
    const float4* __restrict__ pts4,
    const float* __restrict__ feat,
    const float* __restrict__ Wq, const float* __restrict__ Wk, const float* __restrict__ Wv,
    const float* __restrict__ Wp1, const float* __restrict__ gp, const float* __restrict__ bp,
    const float* __restrict__ Wp2, const float* __restrict__ Wa1, const float* __restrict__ Wa2,
    const float* __restrict__ ga1, const float* __restrict__ ba1,
    const float* __restrict__ ga2, const float* __restrict__ ba2, const float* __restrict__ b_a2,
    int* __restrict__ sidx,
    float* __restrict__ fq, float* __restrict__ fk, float* __restrict__ fv,
    int* __restrict__ kidx, float* __restrict__ y, float* __restrict__ yn,
    float* __restrict__ skip,
    float* __restrict__ psv, int* __restrict__ psi,
    float* __restrict__ stRel, float* __restrict__ stX, float* __restrict__ stX1,
    int* __restrict__ wctr)
{
  // union: FPS xy[16384] float2 = 128KB (+reduce scratch); workers use <=32KB
  __shared__ __align__(16) char smem[131200];
  const int tid = threadIdx.x;

  if (blockIdx.x == 0) {
    #pragma clang fp contract(off)
    float2* xy  = (float2*)smem;
    float*  rbv = (float*)(smem + 131072);
    int*    rbi = (int*)  (smem + 131072 + 32);
    const int t = tid;                 // 0..511
    float z[32], dm[32];
    #pragma unroll
    for (int m=0;m<32;m++){
      float4 p = pts4[t*32+m];
      xy[m*512+t] = make_float2(p.x, p.y);
      z[m] = p.z;
      dm[m] = 1e10f;
    }
    #pragma unroll
    for (int m=0;m<32;m++) asm volatile("" : "+v"(z[m]));   // forbid remat of z
    __syncthreads();
    int far = 0;
    float4 f0 = pts4[0];
    float fx=f0.x, fy=f0.y, fz=f0.z;
    for (int s=0;s<SP;s++){
      if (t==0) sidx[s]=far;
      float bv=-1.f; int bi=0;
      #pragma unroll
      for (int m=0;m<32;m++){
        float2 p = xy[m*512+t];
        float dx=p.x-fx, dy=p.y-fy, dz=z[m]-fz;
        float q0=dx*dx, q1=dy*dy, q2=dz*dz;
        float d=(q0+q1)+q2;                 // reference assoc, no FMA
        float nd=fminf(dm[m],d);
        dm[m]=nd;
        bool g = nd>bv;                     // strict: ties keep lower index
        bv = g?nd:bv;
        bi = g?(t*32+m):bi;
      }
      #pragma unroll
      for (int o=1;o<64;o<<=1){
        float ov=__shfl_xor(bv,o); int oi=__shfl_xor(bi,o);
        bool g = (ov>bv)||((ov==bv)&&(oi<bi));
        bv=g?ov:bv; bi=g?oi:bi;
      }
      __syncthreads();
      if ((t&63)==0){ rbv[t>>6]=bv; rbi[t>>6]=bi; }
      __syncthreads();
      float cv=rbv[t&7]; int ci=rbi[t&7];
      #pragma unroll
      for (int o=1;o<8;o<<=1){
        float ov=__shfl_xor(cv,o); int oi=__shfl_xor(ci,o);
        bool g=(ov>cv)||((ov==cv)&&(oi<ci));
        cv=g?ov:cv; ci=g?oi:ci;
      }
      far = ci;
      float4 fp = pts4[far];
      fx=fp.x; fy=fp.y; fz=fp.z;
    }
    return;
  }

  // ======== workers (512 thr) ========
  const int bid = blockIdx.x - 1;   // 0..NW-1
  const int c = tid & 63;
  const int wv_ = tid >> 6;         // 0..7

  // ---- P0: qkv (units of 8 rows) ----
  for (int u = bid; u < NP/8; u += NW){
    int row = u*8 + wv_;
    const float* f = feat + row*CINCH;
    float aq=0.f, ak=0.f, av=0.f;
    #pragma unroll
    for (int k=0;k<CINCH;k++){
      float fe=f[k];
      aq=fmaf(fe,Wq[k*CO+c],aq); ak=fmaf(fe,Wk[k*CO+c],ak); av=fmaf(fe,Wv[k*CO+c],av);
    }
    fq[row*CO+c]=aq; fk[row*CO+c]=ak; fv[row*CO+c]=av;
  }
  wbar(wctr, 1*NW);

  // ---- P1: knn16 partials: 512 units = (32 query-blocks of 512) x (16 cand parts of 1024) ----
  {
    float4* tile = (float4*)smem;   // 16KB
    for (int u = bid; u < 512; u += NW){
      int qb = u >> 4, part = u & 15;
      int q = qb*512 + tid;
      int c0 = part*1024;
      __syncthreads();
      tile[tid]     = pts4[c0+tid];
      tile[tid+512] = pts4[c0+tid+512];
      __syncthreads();
      float4 tq = pts4[q];
      float qx=tq.x,qy=tq.y,qz=tq.z;
      float v[KK]; int id[KK];
      #pragma unroll
      for (int k=0;k<KK;k++){ v[k]=3.4e38f; id[k]=0x7fffffff; }
      for (int j=0;j<1024;j++){
        float4 cpt=tile[j];
        float dot = qx*cpt.x + qy*cpt.y + qz*cpt.z;
        float s = fmaf(-2.f,dot,cpt.w);
        if (s < v[KK-1]) {
          int gj = c0+j;
          #pragma unroll
          for (int k=KK-1;k>=1;--k){
            bool sh = s < v[k-1];
            bool pl = s < v[k];
            float nv = sh ? v[k-1] : (pl ? s  : v[k]);
            int   ni = sh ? id[k-1] : (pl ? gj : id[k]);
            v[k]=nv; id[k]=ni;
          }
          if (s < v[0]){ v[0]=s; id[0]=gj; }
        }
      }
      size_t o = ((size_t)q*16 + part)*KK;
      #pragma unroll
      for (int k=0;k<KK;k++){ psv[o+k]=v[k]; psi[o+k]=id[k]; }
    }
  }
  wbar(wctr, 2*NW);

  // ---- P2: merge 16 sorted lists -> kidx ----
  for (int q = bid*512 + tid; q < NP; q += NW*512)
    mergeQ<16>(psv + (size_t)q*16*KK, psi + (size_t)q*16*KK, kidx + q*KK);
  wbar(wctr, 3*NW);

  // ---- P3: rel + stats ----
  for (int r = bid*512 + tid; r < NP*KK; r += NW*512){
    int i = r>>4;
    int j = kidx[r];
    float4 pi=pts4[i], pj=pts4[j];
    float rx=pi.x-pj.x, ry=pi.y-pj.y, rz=pi.z-pj.z;
    float sv[3], sq[3];
    #pragma unroll
    for (int cc=0;cc<3;cc++){
      float yc = rx*Wp1[cc] + ry*Wp1[3+cc] + rz*Wp1[6+cc];
      y[r*3+cc]=yc; sv[cc]=yc; sq[cc]=yc*yc;
    }
    #pragma unroll
    for (int cc=0;cc<3;cc++){
      float a=sv[cc], b=sq[cc];
      #pragma unroll
      for (int o=32;o;o>>=1){ a+=__shfl_down(a,o); b+=__shfl_down(b,o); }
      if ((tid&63)==0){ atomicAdd(&stRel[cc],a); atomicAdd(&stRel[3+cc],b); }
    }
  }
  wbar(wctr, 4*NW);

  // ---- P4: yn = relu(bn(y)) ----
  {
    const float invn = 1.f/(float)(NP*KK);
    for (int r = bid*512 + tid; r < NP*KK; r += NW*512){
      #pragma unroll
      for (int cc=0;cc<3;cc++){
        float m = stRel[cc]*invn;
        float var = stRel[3+cc]*invn - m*m;
        float rs = 1.f/sqrtf(var+1e-5f);
        float tt = (y[r*3+cc]-m)*rs;
        tt = fmaf(tt, gp[cc], bp[cc]);
        yn[r*3+cc] = fmaxf(tt,0.f);
      }
    }
  }
  wbar(wctr, 5*NW);

  // ---- P5: xstats (512 units x 8 waves x 64 rows = NP*KK) ----
  {
    float* red = (float*)(smem + 16384);   // [2][8][64] = 4KB
    float w0=Wp2[c], w1=Wp2[64+c], w2=Wp2[128+c];
    float s=0.f,sq=0.f;
    for (int u = bid; u < 512; u += NW){
      int row0 = (u*8 + wv_)*64;
      for (int q2=0;q2<64;q2++){
        int r=row0+q2; int p=r>>4; int j=kidx[r];
        float y0=yn[r*3], y1=yn[r*3+1], y2=yn[r*3+2];
        float x = fq[p*CO+c]-fk[j*CO+c]+(y0*w0+y1*w1+y2*w2);
        s+=x; sq=fmaf(x,x,sq);
      }
    }
    red[(0*8+wv_)*64+c]=s; red[(1*8+wv_)*64+c]=sq;
    __syncthreads();
    if (wv_==0){
      float a=0.f,b=0.f;
      #pragma unroll
      for (int u=0;u<8;u++){ a+=red[(0*8+u)*64+c]; b+=red[(1*8+u)*64+c]; }
      atomicAdd(&stX[c],a); atomicAdd(&stX[64+c],b);
    }
  }
  wbar(wctr, 6*NW);

  // ---- P6: x1stats ----
  {
    float* wa1 = (float*)smem;
    float* red = (float*)(smem + 16384);
    for (int u=tid; u<4096; u+=512) wa1[u]=Wa1[u];
    __syncthreads();
    const float invn=1.f/(float)(NP*KK);
    float m1=stX[c]*invn; float vv=stX[64+c]*invn-m1*m1; float rs1=1.f/sqrtf(vv+1e-5f);
    float g1=ga1[c], bb1=ba1[c];
    float w0=Wp2[c],w1=Wp2[64+c],w2=Wp2[128+c];
    float s=0.f,sq=0.f;
    for (int u = bid; u < 512; u += NW){
      int row0 = (u*8 + wv_)*64;
      for (int q2=0;q2<64;q2++){
        int r=row0+q2; int p=r>>4; int j=kidx[r];
        float y0=yn[r*3],y1=yn[r*3+1],y2=yn[r*3+2];
        float x = fq[p*CO+c]-fk[j*CO+c]+(y0*w0+y1*w1+y2*w2);
        float tt=(x-m1)*rs1; tt=fmaxf(fmaf(tt,g1,bb1),0.f);
        float x1 = waveGemm64(tt, wa1, c);
        s += x1; sq = fmaf(x1,x1,sq);
      }
    }
    red[(0*8+wv_)*64+c]=s; red[(1*8+wv_)*64+c]=sq;
    __syncthreads();
    if (wv_==0){
      float a=0.f,b=0.f;
      #pragma unroll
      for (int u=0;u<8;u++){ a+=red[(0*8+u)*64+c]; b+=red[(1*8+u)*64+c]; }
      atomicAdd(&stX1[c],a); atomicAdd(&stX1[64+c],b);
    }
  }
  wbar(wctr, 7*NW);

  // ---- P7: attention -> skip ----
  {
    float* wa1 = (float*)smem;
    float* wa2 = (float*)(smem + 16384);
    for (int u=tid; u<4096; u+=512){ wa1[u]=Wa1[u]; wa2[u]=Wa2[u]; }
    __syncthreads();
    const float invn = 1.f/(float)(NP*KK);
    float m1=stX[c]*invn;  float va=stX[64+c]*invn-m1*m1;  float rs1=1.f/sqrtf(va+1e-5f);
    float m2=stX1[c]*invn; float vb=stX1[64+c]*invn-m2*m2; float rs2=1.f/sqrtf(vb+1e-5f);
    float g1=ga1[c], bb1=ba1[c], g2=ga2[c], bb2=ba2[c], bc=b_a2[c];
    float w0=Wp2[c], w1=Wp2[64+c], w2=Wp2[128+c];
    for (int u = bid; u < NP/8; u += NW){
      int p = u*8 + wv_;
      float fqv = fq[p*CO+c];
      float ex[16];
      #pragma unroll
      for (int k=0;k<16;k++){
        int r=p*16+k; int j=kidx[r];
        float y0=yn[r*3],y1=yn[r*3+1],y2=yn[r*3+2];
        float x = fqv - fk[j*CO+c] + (y0*w0+y1*w1+y2*w2);
        float t1 = (x-m1)*rs1; t1 = fmaxf(fmaf(t1,g1,bb1),0.f);
        float x1 = waveGemm64(t1, wa1, c);
        float t2 = (x1-m2)*rs2; t2 = fmaxf(fmaf(t2,g2,bb2),0.f);
        ex[k] = waveGemm64(t2, wa2, c) + bc;
      }
      float mx = ex[0];
      #pragma unroll
      for (int k=1;k<16;k++) mx = fmaxf(mx, ex[k]);
      float sum=0.f;
      #pragma unroll
      for (int k=0;k<16;k++){ ex[k]=expf(ex[k]-mx); sum+=ex[k]; }
      float acc=0.f;
      #pragma unroll
      for (int k=0;k<16;k++){
        int r=p*16+k; int j=kidx[r];
        float y0=yn[r*3],y1=yn[r*3+1],y2=yn[r*3+2];
        float rpe = y0*w0+y1*w1+y2*w2;
        acc = fmaf(ex[k], fv[j*CO+c]+rpe, acc);
      }
      skip[p*CO+c] = acc/sum;
    }
  }
}

// ---------------- gather sampled points ----------------
__global__ __launch_bounds__(256) void k_gather(const float4* __restrict__ pts4, const int* __restrict__ sidx,
    float4* __restrict__ spts4) {
  int q = blockIdx.x*256 + threadIdx.x;
  spts4[q] = pts4[sidx[q]];
}

// ---------------- KNN16 partial (standalone, for SP) ----------------
#define KTS 2048
__global__ __launch_bounds__(256,4) void k_knn16p(const float4* __restrict__ qp,
    const float4* __restrict__ cp, int clen,
    float* __restrict__ psv, int* __restrict__ psi) {
  __shared__ float4 tile[KTS];
  int q = blockIdx.x*256 + threadIdx.x;
  int part = blockIdx.y;
  int nspl = gridDim.y;
  int c0 = part*clen;
  float4 tq = qp[q];
  float qx=tq.x, qy=tq.y, qz=tq.z;
  float v[KK]; int id[KK];
  #pragma unroll
  for (int k=0;k<KK;k++){ v[k]=3.4e38f; id[k]=0x7fffffff; }
  for (int base=c0; base<c0+clen; base+=KTS){
    __syncthreads();
    for (int tt=threadIdx.x;tt<KTS;tt+=256) tile[tt]=cp[base+tt];
    __syncthreads();
    for (int j=0;j<KTS;j++){
      float4 cpt=tile[j];
      float dot = qx*cpt.x + qy*cpt.y + qz*cpt.z;
      float s = fmaf(-2.f,dot,cpt.w);
      if (s < v[KK-1]) {
        int gj = base+j;
        #pragma unroll
        for (int k=KK-1;k>=1;--k){
          bool sh = s < v[k-1];
          bool pl = s < v[k];
          float nv = sh ? v[k-1] : (pl ? s  : v[k]);
          int   ni = sh ? id[k-1] : (pl ? gj : id[k]);
          v[k]=nv; id[k]=ni;
        }
        if (s < v[0]){ v[0]=s; id[0]=gj; }
      }
    }
  }
  size_t o = ((size_t)q*nspl + part)*KK;
  #pragma unroll
  for (int k=0;k<KK;k++){ psv[o+k]=v[k]; psi[o+k]=id[k]; }
}

template<int NS>
__global__ __launch_bounds__(256,4) void k_merge(const float* __restrict__ psv,
    const int* __restrict__ psi, int* __restrict__ oidx) {
  int q = blockIdx.x*256 + threadIdx.x;
  mergeQ<NS>(psv + (size_t)q*NS*KK, psi + (size_t)q*NS*KK, oidx + q*KK);
}

// ---------------- TransitionDown pass 1 ----------------
__global__ __launch_bounds__(256) void k_d1(const float* __restrict__ skip, const int* __restrict__ idx2,
    const float* __restrict__ Wd1, float* __restrict__ t1, float* __restrict__ st) {
  __shared__ float wl[4096];
  __shared__ float red[2][4][64];
  for (int t=threadIdx.x;t<4096;t+=256) wl[t]=Wd1[t];
  int w=threadIdx.x>>6, c=threadIdx.x&63;
  __syncthreads();
  float s=0.f,sq=0.f;
  int row0 = blockIdx.x*64 + w*16;
  for (int t=0;t<16;t++){
    int r=row0+t; int src=idx2[r];
    float kf = skip[src*CO+c];
    float o = waveGemm64(kf, wl, c);
    t1[r*CO+c]=o; s+=o; sq=fmaf(o,o,sq);
  }
  red[0][w][c]=s; red[1][w][c]=sq;
  __syncthreads();
  if (w==0){
    float a=red[0][0][c]+red[0][1][c]+red[0][2][c]+red[0][3][c];
    float b=red[1][0][c]+red[1][1][c]+red[1][2][c]+red[1][3][c];
    atomicAdd(&st[c],a); atomicAdd(&st[64+c],b);
  }
}

// ---------------- TransitionDown pass 2 ----------------
__global__ __launch_bounds__(256) void k_d2(const float* __restrict__ t1in, const float* __restrict__ stin,
    const float* __restrict__ gd1, const float* __restrict__ bd1, const float* __restrict__ Wd2,
    float* __restrict__ t2, float* __restrict__ st) {
  __shared__ float wl[4096];
  __shared__ float red[2][4][64];
  for (int t=threadIdx.x;t<4096;t+=256) wl[t]=Wd2[t];
  int w=threadIdx.x>>6, c=threadIdx.x&63;
  const float invn = 1.f/(float)(SP*KK);
  float m=stin[c]*invn; float va=stin[64+c]*invn-m*m; float rs=1.f/sqrtf(va+1e-5f);
  float g=gd1[c], bb=bd1[c];
  __syncthreads();
  float s=0.f,sq=0.f;
  int row0 = blockIdx.x*64 + w*16;
  for (int t=0;t<16;t++){
    int r=row0+t;
    float h = (t1in[r*CO+c]-m)*rs; h = fmaxf(fmaf(h,g,bb),0.f);
    float o = waveGemm64(h, wl, c);
    t2[r*CO+c]=o; s+=o; sq=fmaf(o,o,sq);
  }
  red[0][w][c]=s; red[1][w][c]=sq;
  __syncthreads();
  if (w==0){
    float a=red[0][0][c]+red[0][1][c]+red[0][2][c]+red[0][3][c];
    float b=red[1][0][c]+red[1][1][c]+red[1][2][c]+red[1][3][c];
    atomicAdd(&st[c],a); atomicAdd(&st[64+c],b);
  }
}

// ---------------- down_f / df ----------------
__global__ __launch_bounds__(256) void k_downf(const float* __restrict__ t2, const float* __restrict__ stin,
    const float* __restrict__ gd2, const float* __restrict__ bd2, const float* __restrict__ Wdn,
    const float* __restrict__ bdn, float* __restrict__ df) {
  __shared__ float wl[4096];
  for (int t=threadIdx.x;t<4096;t+=256) wl[t]=Wdn[t];
  int w=threadIdx.x>>6, c=threadIdx.x&63;
  int srow = blockIdx.x*4 + w;
  const float invn = 1.f/(float)(SP*KK);
  float m=stin[c]*invn; float va=stin[64+c]*invn-m*m; float rs=1.f/sqrtf(va+1e-5f);
  float g=gd2[c], bb=bd2[c];
  __syncthreads();
  float mx=-3.4e38f;
  for (int k=0;k<16;k++){
    float h=(t2[(srow*16+k)*CO+c]-m)*rs; h=fmaxf(fmaf(h,g,bb),0.f);
    mx=fmaxf(mx,h);
  }
  float o = waveGemm64(mx, wl, c) + bdn[c];
  df[srow*CO+c]=o;
}

// ---------------- KNN k=3 ----------------
__global__ __launch_bounds__(256,4) void k_knn3(const float4* __restrict__ qp, const float4* __restrict__ cp,
    int* __restrict__ idx3, float* __restrict__ d3) {
  __shared__ float4 tile[2048];
  int q = blockIdx.x*256 + threadIdx.x;
  float4 Q = qp[q];
  float v0=3.4e38f,v1=3.4e38f,v2=3.4e38f;
  int i0=0x7fffffff,i1=0x7fffffff,i2=0x7fffffff;
  for (int base=0;base<SP;base+=2048){
    __syncthreads();
    for (int tt=threadIdx.x;tt<2048;tt+=256) tile[tt]=cp[base+tt];
    __syncthreads();
    for (int j=0;j<2048;j++){
      float4 cpt = tile[j];
      float dot = Q.x*cpt.x + Q.y*cpt.y + Q.z*cpt.z;
      float d = fmaf(-2.f, dot, Q.w) + cpt.w;
      if (d < v2){
        int gj = base+j;
        bool s2 = d < v1;
        bool s1 = d < v0;
        v2 = s2 ? v1 : d;  i2 = s2 ? i1 : gj;
        v1 = s2 ? (s1 ? v0 : d) : v1; i1 = s2 ? (s1 ? i0 : gj) : i1;
        v0 = s1 ? d : v0;  i0 = s1 ? gj : i0;
      }
    }
  }
  idx3[q*3]=i0; idx3[q*3+1]=i1; idx3[q*3+2]=i2;
  d3[q*3]=v0; d3[q*3+1]=v1; d3[q*3+2]=v2;
}

// ---------------- final output ----------------
__global__ __launch_bounds__(256) void k_out(const float* __restrict__ df, const int* __restrict__ idx3,
    const float* __restrict__ d3, const float* __restrict__ skip, const float* __restrict__ Wup,
    const float* __restrict__ bup, float* __restrict__ out) {
  __shared__ float wl[4096];
  for (int t=threadIdx.x;t<4096;t+=256) wl[t]=Wup[t];
  int w=threadIdx.x>>6, c=threadIdx.x&63;
  int i = blockIdx.x*4 + w;
  __syncthreads();
  int j0=idx3[i*3], j1=idx3[i*3+1], j2=idx3[i*3+2];
  float e0=d3[i*3], e1=d3[i*3+1], e2=d3[i*3+2];
  float r0=1.f/(e0+1e-8f), r1=1.f/(e1+1e-8f), r2=1.f/(e2+1e-8f);
  float sm=(r0+r1)+r2;
  float w0=r0/sm, w1=r1/sm, w2=r2/sm;
  float interp = (w0*df[j0*CO+c] + w1*df[j1*CO+c]) + w2*df[j2*CO+c];
  float sk = skip[i*CO+c];
  float up = waveGemm64(sk, wl, c);
  out[i*CO+c] = (interp + up) + bup[c];
}

// ---------------- launch ----------------
extern "C" void kernel_launch(void* const* d_in, const int* in_sizes, int n_in,
                              void* d_out, int out_size, void* d_ws, size_t ws_size,
                              hipStream_t stream) {
  (void)in_sizes; (void)n_in; (void)out_size; (void)ws_size;
  const float* points   = (const float*)d_in[0];
  const float* features = (const float*)d_in[1];
  const float* Wq  = (const float*)d_in[2];
  const float* Wk  = (const float*)d_in[3];
  const float* Wv  = (const float*)d_in[4];
  const float* ga1 = (const float*)d_in[5];
  const float* ba1 = (const float*)d_in[6];
  const float* Wa1 = (const float*)d_in[7];
  const float* ga2 = (const float*)d_in[8];
  const float* ba2 = (const float*)d_in[9];
  const float* Wa2 = (const float*)d_in[10];
  const float* b_a2= (const float*)d_in[11];
  const float* Wp1 = (const float*)d_in[12];
  const float* gp  = (const float*)d_in[13];
  const float* bp  = (const float*)d_in[14];
  const float* Wp2 = (const float*)d_in[15];
  const float* Wd1 = (const float*)d_in[16];
  const float* gd1 = (const float*)d_in[17];
  const float* bd1 = (const float*)d_in[18];
  const float* Wd2 = (const float*)d_in[19];
  const float* gd2 = (const float*)d_in[20];
  const float* bd2 = (const float*)d_in[21];
  const float* Wup = (const float*)d_in[22];
  const float* bup = (const float*)d_in[23];
  const float* Wdn = (const float*)d_in[24];
  const float* bdn = (const float*)d_in[25];
  float* out = (float*)d_out;

  char* wp = (char*)d_ws;
  auto carve = [&](size_t bytes)->char* { char* p = wp; wp += (bytes + 255) & ~(size_t)255; return p; };
  float4* pts4  = (float4*)carve((size_t)NP*16);
  float*  fq    = (float*) carve((size_t)NP*CO*4);
  float*  fk    = (float*) carve((size_t)NP*CO*4);
  float*  fv    = (float*) carve((size_t)NP*CO*4);
  int*    kidx  = (int*)   carve((size_t)NP*KK*4);
  float*  y     = (float*) carve((size_t)NP*KK*3*4);
  float*  yn    = (float*) carve((size_t)NP*KK*3*4);
  float*  skip  = (float*) carve((size_t)NP*CO*4);
  int*    sidx  = (int*)   carve((size_t)SP*4);
  float4* spts4 = (float4*)carve((size_t)SP*16);
  int*    idx2  = (int*)   carve((size_t)SP*KK*4);
  float*  t1    = (float*) carve((size_t)SP*KK*CO*4);   // 16MB: NP psv aliases
  float*  t2    = (float*) carve((size_t)SP*KK*CO*4);   // 16MB: NP psi aliases; later SP bufs
  float*  df    = (float*) carve((size_t)SP*CO*4);
  int*    idx3  = (int*)   carve((size_t)NP*3*4);
  float*  d3    = (float*) carve((size_t)NP*3*4);
  float*  stats = (float*) carve(4096);                 // zeroed each launch
  float* stRel = stats;        // 6 floats
  float* stX   = stats + 8;    // 128
  float* stX1  = stats + 136;  // 128
  float* stD1  = stats + 264;  // 128
  float* stD2  = stats + 392;  // 128
  int*   wctr  = (int*)(stats + 768);
  float* psvNP = t1;          // 16384*16*16*4 = 16MB
  int*   psiNP = (int*)t2;    // 16MB
  float* psvSP = t2;          // SP split bufs reuse t2 after mega
  int*   psiSP = (int*)(t2 + (size_t)SP*8*KK);

  hipMemsetAsync(stats, 0, 4096, stream);

  k_pts4 <<<NP/256, 256, 0, stream>>>(points, pts4);

  k_mega <<<1+NW, 512, 0, stream>>>(pts4, features,
      Wq, Wk, Wv, Wp1, gp, bp, Wp2, Wa1, Wa2, ga1, ba1, ga2, ba2, b_a2,
      sidx, fq, fk, fv, kidx, y, yn, skip, psvNP, psiNP, stRel, stX, stX1, wctr);

  k_gather   <<<SP/256, 256, 0, stream>>>(pts4, sidx, spts4);
  k_knn16p   <<<dim3(SP/256,8), 256, 0, stream>>>(spts4, pts4, NP/8, psvSP, psiSP);
  k_merge<8> <<<SP/256, 256, 0, stream>>>(psvSP, psiSP, idx2);
  k_d1       <<<SP*KK/64, 256, 0, stream>>>(skip, idx2, Wd1, t1, stD1);
  k_d2       <<<SP*KK/64, 256, 0, stream>>>(t1, stD1, gd1, bd1, Wd2, t2, stD2);
  k_downf    <<<SP/4,   256, 0, stream>>>(t2, stD2, gd2, bd2, Wdn, bdn, df);
  k_knn3     <<<NP/256, 256, 0, stream>>>(pts4, spts4, idx3, d3);
  k_out      <<<NP/4,   256, 0, stream>>>(df, idx3, d3, skip, Wup, bup, out);
}